// Round 1
// baseline (10884.144 us; speedup 1.0000x reference)
//
#include <hip/hip_runtime.h>

#define HID 6
#define NUM_GRAPHS 1000

// ---------------------------------------------------------------------------
// Edge pass: m = relu(h[src] + edge_attr); atomicAdd into agg[dst]
// ---------------------------------------------------------------------------
__global__ void edge_kernel(const float* __restrict__ h,
                            const float* __restrict__ edge_attr,
                            const int* __restrict__ src,
                            const int* __restrict__ dst,
                            float* __restrict__ agg,
                            int E) {
    int e = blockIdx.x * blockDim.x + threadIdx.x;
    if (e >= E) return;
    int s = src[e];
    int d = dst[e];

    const float2* ea = (const float2*)(edge_attr + (size_t)e * HID);
    const float2* hs = (const float2*)(h + (size_t)s * HID);
    float2 a0 = ea[0], a1 = ea[1], a2 = ea[2];
    float2 h0 = hs[0], h1 = hs[1], h2 = hs[2];

    float m0 = fmaxf(h0.x + a0.x, 0.0f);
    float m1 = fmaxf(h0.y + a0.y, 0.0f);
    float m2 = fmaxf(h1.x + a1.x, 0.0f);
    float m3 = fmaxf(h1.y + a1.y, 0.0f);
    float m4 = fmaxf(h2.x + a2.x, 0.0f);
    float m5 = fmaxf(h2.y + a2.y, 0.0f);

    float* ag = agg + (size_t)d * HID;
    atomicAdd(ag + 0, m0);
    atomicAdd(ag + 1, m1);
    atomicAdd(ag + 2, m2);
    atomicAdd(ag + 3, m3);
    atomicAdd(ag + 4, m4);
    atomicAdd(ag + 5, m5);
}

// ---------------------------------------------------------------------------
// Node update: out = (h + agg) @ W + b, optional relu
// ---------------------------------------------------------------------------
__global__ void node_kernel(const float* __restrict__ h,
                            const float* __restrict__ agg,
                            const float* __restrict__ W,
                            const float* __restrict__ b,
                            float* __restrict__ out,
                            int N, int do_relu) {
    __shared__ float sW[HID * HID];
    __shared__ float sb[HID];
    if (threadIdx.x < HID * HID) sW[threadIdx.x] = W[threadIdx.x];
    if (threadIdx.x < HID) sb[threadIdx.x] = b[threadIdx.x];
    __syncthreads();

    int i = blockIdx.x * blockDim.x + threadIdx.x;
    if (i >= N) return;

    const float2* hp = (const float2*)(h + (size_t)i * HID);
    const float2* ap = (const float2*)(agg + (size_t)i * HID);
    float t[HID];
    {
        float2 v0 = hp[0], v1 = hp[1], v2 = hp[2];
        float2 g0 = ap[0], g1 = ap[1], g2 = ap[2];
        t[0] = v0.x + g0.x; t[1] = v0.y + g0.y;
        t[2] = v1.x + g1.x; t[3] = v1.y + g1.y;
        t[4] = v2.x + g2.x; t[5] = v2.y + g2.y;
    }

    float o[HID];
#pragma unroll
    for (int d = 0; d < HID; ++d) o[d] = sb[d];
#pragma unroll
    for (int k = 0; k < HID; ++k) {
#pragma unroll
        for (int d = 0; d < HID; ++d) o[d] += t[k] * sW[k * HID + d];
    }
    if (do_relu) {
#pragma unroll
        for (int d = 0; d < HID; ++d) o[d] = fmaxf(o[d], 0.0f);
    }

    float2* op = (float2*)(out + (size_t)i * HID);
    op[0] = make_float2(o[0], o[1]);
    op[1] = make_float2(o[2], o[3]);
    op[2] = make_float2(o[4], o[5]);
}

// ---------------------------------------------------------------------------
// Mean-pool accumulation: batch is sorted, so most waves are graph-uniform.
// Fast path: wave shuffle-reduce + 1 atomic per dim per wave.
// ---------------------------------------------------------------------------
__global__ void pool_kernel(const float* __restrict__ h,
                            const int* __restrict__ batch,
                            float* __restrict__ sums,   // [G*HID]
                            float* __restrict__ cnts,   // [G]
                            int N) {
    int i = blockIdx.x * blockDim.x + threadIdx.x;
    int lane = threadIdx.x & 63;
    bool active = (i < N);

    float v[HID];
    int g = -1;
    if (active) {
        g = batch[i];
        const float2* hp = (const float2*)(h + (size_t)i * HID);
        float2 v0 = hp[0], v1 = hp[1], v2 = hp[2];
        v[0] = v0.x; v[1] = v0.y; v[2] = v1.x; v[3] = v1.y; v[4] = v2.x; v[5] = v2.y;
    } else {
#pragma unroll
        for (int d = 0; d < HID; ++d) v[d] = 0.0f;
    }

    int g0 = __shfl(g, 0);
    bool uniform = __all(active) && __all(g == g0);
    if (uniform) {
#pragma unroll
        for (int d = 0; d < HID; ++d) {
            float s = v[d];
            for (int off = 32; off > 0; off >>= 1) s += __shfl_down(s, off);
            if (lane == 0) atomicAdd(&sums[(size_t)g0 * HID + d], s);
        }
        if (lane == 0) atomicAdd(&cnts[g0], 64.0f);
    } else if (active) {
#pragma unroll
        for (int d = 0; d < HID; ++d) atomicAdd(&sums[(size_t)g * HID + d], v[d]);
        atomicAdd(&cnts[g], 1.0f);
    }
}

// ---------------------------------------------------------------------------
// Final: out[g] = (sums[g]/max(cnt,1)) . Wl + bl
// ---------------------------------------------------------------------------
__global__ void out_kernel(const float* __restrict__ sums,
                           const float* __restrict__ cnts,
                           const float* __restrict__ Wl,
                           const float* __restrict__ bl,
                           float* __restrict__ out) {
    int gI = blockIdx.x * blockDim.x + threadIdx.x;
    if (gI >= NUM_GRAPHS) return;
    float c = fmaxf(cnts[gI], 1.0f);
    float acc = bl[0];
#pragma unroll
    for (int d = 0; d < HID; ++d) acc += (sums[(size_t)gI * HID + d] / c) * Wl[d];
    out[gI] = acc;
}

extern "C" void kernel_launch(void* const* d_in, const int* in_sizes, int n_in,
                              void* d_out, int out_size, void* d_ws, size_t ws_size,
                              hipStream_t stream) {
    const float* x         = (const float*)d_in[0];
    const int*   eidx      = (const int*)d_in[1];
    const float* edge_attr = (const float*)d_in[2];
    const int*   batch     = (const int*)d_in[3];
    const float* W1 = (const float*)d_in[4];
    const float* b1 = (const float*)d_in[5];
    const float* W2 = (const float*)d_in[6];
    const float* b2 = (const float*)d_in[7];
    const float* W3 = (const float*)d_in[8];
    const float* b3 = (const float*)d_in[9];
    const float* Wl = (const float*)d_in[10];
    const float* bl = (const float*)d_in[11];

    const int N = in_sizes[0] / HID;
    const int E = in_sizes[1] / 2;

    float* agg  = (float*)d_ws;                 // N*HID
    float* hA   = agg + (size_t)N * HID;        // N*HID
    float* hB   = hA  + (size_t)N * HID;        // N*HID
    float* sums = hB  + (size_t)N * HID;        // G*HID
    float* cnts = sums + (size_t)NUM_GRAPHS * HID;  // G

    const int* src = eidx;
    const int* dst = eidx + E;

    const int TB = 256;
    const int ebl = (E + TB - 1) / TB;
    const int nbl = (N + TB - 1) / TB;
    const size_t aggBytes = (size_t)N * HID * sizeof(float);

    // Layer 1: x -> hA (relu)
    hipMemsetAsync(agg, 0, aggBytes, stream);
    edge_kernel<<<ebl, TB, 0, stream>>>(x, edge_attr, src, dst, agg, E);
    node_kernel<<<nbl, TB, 0, stream>>>(x, agg, W1, b1, hA, N, 1);

    // Layer 2: hA -> hB (relu)
    hipMemsetAsync(agg, 0, aggBytes, stream);
    edge_kernel<<<ebl, TB, 0, stream>>>(hA, edge_attr, src, dst, agg, E);
    node_kernel<<<nbl, TB, 0, stream>>>(hA, agg, W2, b2, hB, N, 1);

    // Layer 3: hB -> hA (no relu)
    hipMemsetAsync(agg, 0, aggBytes, stream);
    edge_kernel<<<ebl, TB, 0, stream>>>(hB, edge_attr, src, dst, agg, E);
    node_kernel<<<nbl, TB, 0, stream>>>(hB, agg, W3, b3, hA, N, 0);

    // Pool + output
    hipMemsetAsync(sums, 0, (size_t)(NUM_GRAPHS * HID + NUM_GRAPHS) * sizeof(float), stream);
    pool_kernel<<<nbl, TB, 0, stream>>>(hA, batch, sums, cnts, N);
    out_kernel<<<(NUM_GRAPHS + TB - 1) / TB, TB, 0, stream>>>(sums, cnts, Wl, bl, (float*)d_out);
}

// Round 2
// 2929.347 us; speedup vs baseline: 3.7156x; 3.7156x over previous
//
#include <hip/hip_runtime.h>

#define HID 6
#define NUM_GRAPHS 1000
#define SCAN_B 1024

// ===========================================================================
// CSR build
// ===========================================================================
__global__ void hist_kernel(const int* __restrict__ dst, int* __restrict__ deg, int E) {
    int e = blockIdx.x * blockDim.x + threadIdx.x;
    if (e < E) atomicAdd(&deg[dst[e]], 1);
}

// In-place exclusive block scan (Hillis-Steele). data[i] -> exclusive scan within
// its 1024-block; blockSums[b] = block total (if non-null).
__global__ void scan_block_kernel(int* __restrict__ data, int* __restrict__ blockSums, int N) {
    __shared__ int tmp[SCAN_B];
    int t = threadIdx.x;
    int i = blockIdx.x * SCAN_B + t;
    int v = (i < N) ? data[i] : 0;
    tmp[t] = v;
    __syncthreads();
    for (int off = 1; off < SCAN_B; off <<= 1) {
        int a = (t >= off) ? tmp[t - off] : 0;
        __syncthreads();
        tmp[t] += a;
        __syncthreads();
    }
    if (i < N) data[i] = tmp[t] - v;             // exclusive
    if (blockSums && t == SCAN_B - 1) blockSums[blockIdx.x] = tmp[SCAN_B - 1];
}

// rowStart[i] = scanned[i] + blockOffsets[i/1024]; cursor[i] = same; rowStart[N] = E.
__global__ void scan_finish_kernel(const int* __restrict__ scanned,
                                   const int* __restrict__ blockOffsets,
                                   int* __restrict__ rowStart, int* __restrict__ cursor,
                                   int N, int E) {
    int i = blockIdx.x * blockDim.x + threadIdx.x;
    if (i < N) {
        int v = scanned[i] + blockOffsets[i >> 10];
        rowStart[i] = v;
        cursor[i] = v;
    }
    if (i == 0) rowStart[N] = E;
}

__global__ void scatter_kernel(const int* __restrict__ src, const int* __restrict__ dst,
                               const float* __restrict__ ea,
                               int* __restrict__ cursor,
                               int* __restrict__ src_perm, float* __restrict__ ea_perm,
                               int E) {
    int e = blockIdx.x * blockDim.x + threadIdx.x;
    if (e >= E) return;
    int d = dst[e];
    int pos = atomicAdd(&cursor[d], 1);
    src_perm[pos] = src[e];
    const float2* s = (const float2*)(ea + (size_t)e * HID);
    float2 a0 = s[0], a1 = s[1], a2 = s[2];
    float2* o = (float2*)(ea_perm + (size_t)pos * HID);
    o[0] = a0; o[1] = a1; o[2] = a2;
}

// ===========================================================================
// Fused GINE layer (CSR gather + node update), no atomics.
// ===========================================================================
__global__ void layer_kernel(const float* __restrict__ h,
                             const float* __restrict__ ea_perm,
                             const int* __restrict__ src_perm,
                             const int* __restrict__ rowStart,
                             const float* __restrict__ W, const float* __restrict__ b,
                             float* __restrict__ out, int N, int do_relu) {
    __shared__ float sW[HID * HID];
    __shared__ float sb[HID];
    if (threadIdx.x < HID * HID) sW[threadIdx.x] = W[threadIdx.x];
    if (threadIdx.x < HID) sb[threadIdx.x] = b[threadIdx.x];
    __syncthreads();

    int i = blockIdx.x * blockDim.x + threadIdx.x;
    if (i >= N) return;

    int beg = rowStart[i], end = rowStart[i + 1];

    float t[HID];
    {
        const float2* hp = (const float2*)(h + (size_t)i * HID);
        float2 h0 = hp[0], h1 = hp[1], h2 = hp[2];
        t[0] = h0.x; t[1] = h0.y; t[2] = h1.x; t[3] = h1.y; t[4] = h2.x; t[5] = h2.y;
    }

    for (int k = beg; k < end; ++k) {
        int s = src_perm[k];
        const float2* hs = (const float2*)(h + (size_t)s * HID);
        const float2* ap = (const float2*)(ea_perm + (size_t)k * HID);
        float2 b0 = hs[0], b1 = hs[1], b2 = hs[2];
        float2 a0 = ap[0], a1 = ap[1], a2 = ap[2];
        t[0] += fmaxf(b0.x + a0.x, 0.0f);
        t[1] += fmaxf(b0.y + a0.y, 0.0f);
        t[2] += fmaxf(b1.x + a1.x, 0.0f);
        t[3] += fmaxf(b1.y + a1.y, 0.0f);
        t[4] += fmaxf(b2.x + a2.x, 0.0f);
        t[5] += fmaxf(b2.y + a2.y, 0.0f);
    }

    float o[HID];
#pragma unroll
    for (int d = 0; d < HID; ++d) o[d] = sb[d];
#pragma unroll
    for (int k = 0; k < HID; ++k) {
#pragma unroll
        for (int d = 0; d < HID; ++d) o[d] += t[k] * sW[k * HID + d];
    }
    if (do_relu) {
#pragma unroll
        for (int d = 0; d < HID; ++d) o[d] = fmaxf(o[d], 0.0f);
    }

    float2* op = (float2*)(out + (size_t)i * HID);
    op[0] = make_float2(o[0], o[1]);
    op[1] = make_float2(o[2], o[3]);
    op[2] = make_float2(o[4], o[5]);
}

// ===========================================================================
// Fallback path kernels (atomic-based), used only if ws_size is too small.
// ===========================================================================
__global__ void edge_kernel(const float* __restrict__ h, const float* __restrict__ edge_attr,
                            const int* __restrict__ src, const int* __restrict__ dst,
                            float* __restrict__ agg, int E) {
    int e = blockIdx.x * blockDim.x + threadIdx.x;
    if (e >= E) return;
    int s = src[e], d = dst[e];
    const float2* ea = (const float2*)(edge_attr + (size_t)e * HID);
    const float2* hs = (const float2*)(h + (size_t)s * HID);
    float2 a0 = ea[0], a1 = ea[1], a2 = ea[2];
    float2 h0 = hs[0], h1 = hs[1], h2 = hs[2];
    float* ag = agg + (size_t)d * HID;
    atomicAdd(ag + 0, fmaxf(h0.x + a0.x, 0.0f));
    atomicAdd(ag + 1, fmaxf(h0.y + a0.y, 0.0f));
    atomicAdd(ag + 2, fmaxf(h1.x + a1.x, 0.0f));
    atomicAdd(ag + 3, fmaxf(h1.y + a1.y, 0.0f));
    atomicAdd(ag + 4, fmaxf(h2.x + a2.x, 0.0f));
    atomicAdd(ag + 5, fmaxf(h2.y + a2.y, 0.0f));
}

__global__ void node_kernel(const float* __restrict__ h, const float* __restrict__ agg,
                            const float* __restrict__ W, const float* __restrict__ b,
                            float* __restrict__ out, int N, int do_relu) {
    __shared__ float sW[HID * HID];
    __shared__ float sb[HID];
    if (threadIdx.x < HID * HID) sW[threadIdx.x] = W[threadIdx.x];
    if (threadIdx.x < HID) sb[threadIdx.x] = b[threadIdx.x];
    __syncthreads();
    int i = blockIdx.x * blockDim.x + threadIdx.x;
    if (i >= N) return;
    const float2* hp = (const float2*)(h + (size_t)i * HID);
    const float2* ap = (const float2*)(agg + (size_t)i * HID);
    float t[HID];
    float2 v0 = hp[0], v1 = hp[1], v2 = hp[2];
    float2 g0 = ap[0], g1 = ap[1], g2 = ap[2];
    t[0] = v0.x + g0.x; t[1] = v0.y + g0.y;
    t[2] = v1.x + g1.x; t[3] = v1.y + g1.y;
    t[4] = v2.x + g2.x; t[5] = v2.y + g2.y;
    float o[HID];
#pragma unroll
    for (int d = 0; d < HID; ++d) o[d] = sb[d];
#pragma unroll
    for (int k = 0; k < HID; ++k)
#pragma unroll
        for (int d = 0; d < HID; ++d) o[d] += t[k] * sW[k * HID + d];
    if (do_relu)
#pragma unroll
        for (int d = 0; d < HID; ++d) o[d] = fmaxf(o[d], 0.0f);
    float2* op = (float2*)(out + (size_t)i * HID);
    op[0] = make_float2(o[0], o[1]);
    op[1] = make_float2(o[2], o[3]);
    op[2] = make_float2(o[4], o[5]);
}

// ===========================================================================
// Pool + output
// ===========================================================================
__global__ void pool_kernel(const float* __restrict__ h, const int* __restrict__ batch,
                            float* __restrict__ sums, float* __restrict__ cnts, int N) {
    int i = blockIdx.x * blockDim.x + threadIdx.x;
    int lane = threadIdx.x & 63;
    bool active = (i < N);
    float v[HID];
    int g = -1;
    if (active) {
        g = batch[i];
        const float2* hp = (const float2*)(h + (size_t)i * HID);
        float2 v0 = hp[0], v1 = hp[1], v2 = hp[2];
        v[0] = v0.x; v[1] = v0.y; v[2] = v1.x; v[3] = v1.y; v[4] = v2.x; v[5] = v2.y;
    } else {
#pragma unroll
        for (int d = 0; d < HID; ++d) v[d] = 0.0f;
    }
    int g0 = __shfl(g, 0);
    bool uniform = __all(active) && __all(g == g0);
    if (uniform) {
#pragma unroll
        for (int d = 0; d < HID; ++d) {
            float s = v[d];
            for (int off = 32; off > 0; off >>= 1) s += __shfl_down(s, off);
            if (lane == 0) atomicAdd(&sums[(size_t)g0 * HID + d], s);
        }
        if (lane == 0) atomicAdd(&cnts[g0], 64.0f);
    } else if (active) {
#pragma unroll
        for (int d = 0; d < HID; ++d) atomicAdd(&sums[(size_t)g * HID + d], v[d]);
        atomicAdd(&cnts[g], 1.0f);
    }
}

__global__ void out_kernel(const float* __restrict__ sums, const float* __restrict__ cnts,
                           const float* __restrict__ Wl, const float* __restrict__ bl,
                           float* __restrict__ out) {
    int gI = blockIdx.x * blockDim.x + threadIdx.x;
    if (gI >= NUM_GRAPHS) return;
    float c = fmaxf(cnts[gI], 1.0f);
    float acc = bl[0];
#pragma unroll
    for (int d = 0; d < HID; ++d) acc += (sums[(size_t)gI * HID + d] / c) * Wl[d];
    out[gI] = acc;
}

// ===========================================================================
extern "C" void kernel_launch(void* const* d_in, const int* in_sizes, int n_in,
                              void* d_out, int out_size, void* d_ws, size_t ws_size,
                              hipStream_t stream) {
    const float* x         = (const float*)d_in[0];
    const int*   eidx      = (const int*)d_in[1];
    const float* edge_attr = (const float*)d_in[2];
    const int*   batch     = (const int*)d_in[3];
    const float* W1 = (const float*)d_in[4];
    const float* b1 = (const float*)d_in[5];
    const float* W2 = (const float*)d_in[6];
    const float* b2 = (const float*)d_in[7];
    const float* W3 = (const float*)d_in[8];
    const float* b3 = (const float*)d_in[9];
    const float* Wl = (const float*)d_in[10];
    const float* bl = (const float*)d_in[11];

    const int N = in_sizes[0] / HID;
    const int E = in_sizes[1] / 2;
    const int* src = eidx;
    const int* dst = eidx + E;

    const int TB = 256;
    const int ebl = (E + TB - 1) / TB;
    const int nbl = (N + TB - 1) / TB;

    // ---- workspace layout (bytes, all 8-aligned) ----
    char* w = (char*)d_ws;
    size_t off = 0;
    auto alloc = [&](size_t bytes) { void* p = w + off; off += (bytes + 7) & ~(size_t)7; return p; };

    float* hA      = (float*)alloc((size_t)N * HID * sizeof(float));
    float* hB      = (float*)alloc((size_t)N * HID * sizeof(float));
    float* sums    = (float*)alloc((size_t)NUM_GRAPHS * HID * sizeof(float));
    float* cnts    = (float*)alloc((size_t)NUM_GRAPHS * sizeof(float));
    size_t baseOff = off;

    float* ea_perm  = (float*)alloc((size_t)E * HID * sizeof(float));
    int*   src_perm = (int*)alloc((size_t)E * sizeof(int));
    int*   deg      = (int*)alloc((size_t)N * sizeof(int));       // becomes scanned
    int*   rowStart = (int*)alloc((size_t)(N + 2) * sizeof(int));
    int*   cursor   = (int*)alloc((size_t)N * sizeof(int));
    int*   blockSums= (int*)alloc((size_t)SCAN_B * sizeof(int));
    size_t csrNeed  = off;

    if (ws_size >= csrNeed) {
        // ================= CSR path =================
        int scanBlocks = (N + SCAN_B - 1) / SCAN_B;   // 977 for N=1M (<=1024)

        hipMemsetAsync(deg, 0, (size_t)N * sizeof(int), stream);
        hipMemsetAsync(blockSums, 0, (size_t)SCAN_B * sizeof(int), stream);
        hist_kernel<<<ebl, TB, 0, stream>>>(dst, deg, E);
        scan_block_kernel<<<scanBlocks, SCAN_B, 0, stream>>>(deg, blockSums, N);
        scan_block_kernel<<<1, SCAN_B, 0, stream>>>(blockSums, nullptr, scanBlocks);
        scan_finish_kernel<<<nbl, TB, 0, stream>>>(deg, blockSums, rowStart, cursor, N, E);
        scatter_kernel<<<ebl, TB, 0, stream>>>(src, dst, edge_attr, cursor, src_perm, ea_perm, E);

        layer_kernel<<<nbl, TB, 0, stream>>>(x,  ea_perm, src_perm, rowStart, W1, b1, hA, N, 1);
        layer_kernel<<<nbl, TB, 0, stream>>>(hA, ea_perm, src_perm, rowStart, W2, b2, hB, N, 1);
        layer_kernel<<<nbl, TB, 0, stream>>>(hB, ea_perm, src_perm, rowStart, W3, b3, hA, N, 0);
    } else {
        // ================= fallback atomic path =================
        float* agg = (float*)((char*)d_ws + baseOff);   // N*HID floats
        const size_t aggBytes = (size_t)N * HID * sizeof(float);

        hipMemsetAsync(agg, 0, aggBytes, stream);
        edge_kernel<<<ebl, TB, 0, stream>>>(x, edge_attr, src, dst, agg, E);
        node_kernel<<<nbl, TB, 0, stream>>>(x, agg, W1, b1, hA, N, 1);

        hipMemsetAsync(agg, 0, aggBytes, stream);
        edge_kernel<<<ebl, TB, 0, stream>>>(hA, edge_attr, src, dst, agg, E);
        node_kernel<<<nbl, TB, 0, stream>>>(hA, agg, W2, b2, hB, N, 1);

        hipMemsetAsync(agg, 0, aggBytes, stream);
        edge_kernel<<<ebl, TB, 0, stream>>>(hB, edge_attr, src, dst, agg, E);
        node_kernel<<<nbl, TB, 0, stream>>>(hB, agg, W3, b3, hA, N, 0);
    }

    hipMemsetAsync(sums, 0, (size_t)NUM_GRAPHS * HID * sizeof(float), stream);
    hipMemsetAsync(cnts, 0, (size_t)NUM_GRAPHS * sizeof(float), stream);
    pool_kernel<<<nbl, TB, 0, stream>>>(hA, batch, sums, cnts, N);
    out_kernel<<<(NUM_GRAPHS + TB - 1) / TB, TB, 0, stream>>>(sums, cnts, Wl, bl, (float*)d_out);
}